// Round 9
// baseline (173.423 us; speedup 1.0000x reference)
//
#include <hip/hip_runtime.h>
#include <hip/hip_bf16.h>

// Problem constants: B=8, N=1024, T=64, C=16, OC=16, E=16384
#define BB  8
#define NN  1024
#define TT  64
#define CC  16
#define OCC 16
#define EE  16384
#define CHO 80

typedef float  f32x4  __attribute__((ext_vector_type(4)));
typedef __bf16 bf16x8 __attribute__((ext_vector_type(8)));

// fast tanh: tanh(v) = 1 - 2/(e^{2v}+1); inf-safe both ends.
static __device__ __forceinline__ float tanh_fast(float v) {
    float e = __expf(2.0f * v);
    return 1.0f - 2.0f * __builtin_amdgcn_rcpf(e + 1.0f);
}
static __device__ __forceinline__ unsigned pk_bf16(float a, float b) {
    unsigned short lo = __builtin_bit_cast(unsigned short, (__bf16)a);
    unsigned short hi = __builtin_bit_cast(unsigned short, (__bf16)b);
    return (unsigned)lo | ((unsigned)hi << 16);
}

// ---------------- fused prep ----------------
// block 0: graph CSR. blocks 1..12: WTg[64oc][192k] bf16. block 13: wgT, bg, bcat, wslT.

__global__ __launch_bounds__(1024) void k_prep(
    const int* __restrict__ ei,
    const float* __restrict__ w2,  const float* __restrict__ b2,
    const float* __restrict__ w3,  const float* __restrict__ b3,
    const float* __restrict__ w6,  const float* __restrict__ b6,
    const float* __restrict__ w12, const float* __restrict__ b12,
    const float* __restrict__ wg,  const float* __restrict__ bg,
    const float* __restrict__ wsl,
    int* __restrict__ offg, int* __restrict__ cntg, float* __restrict__ dinvg,
    int* __restrict__ src, float* __restrict__ wE,
    float* __restrict__ wgT, float* __restrict__ bgp, float* __restrict__ bcat,
    float* __restrict__ wslT, __bf16* __restrict__ wtg) {
    int tid = threadIdx.x, bid = blockIdx.x;
    const float* wsrc[4] = {w2, w3, w6, w12};
    const float* bsrc[4] = {b2, b3, b6, b12};
    const int ksA[4] = {2, 3, 6, 12};
    const int plA[4] = {0, 1, 2, 6};
    if (bid == 13) {
        if (tid < 256) wgT[tid] = wg[(tid & 15) * CC + (tid >> 4)];
        else if (tid < 272) bgp[tid - 256] = bg[tid - 256];
        else if (tid < 336) { int j = tid - 272; bcat[j] = bsrc[j >> 4][j & 15]; }
        for (int e = tid; e < 4096; e += 1024)           // wslT[t][s] = wsl[s][t]
            wslT[e] = wsl[(e & 63) * 64 + (e >> 6)];
        return;
    }
    if (bid != 0) {    // WTg: e in [0, 12288)
        int e = (bid - 1) * 1024 + tid;
        int j = e / 192, kk = e - j * 192;
        int d = kk >> 4, c = kk & 15;
        int br = j >> 4, oc = j & 15;
        int k = d - 6 + plA[br];
        float v = (k >= 0 && k < ksA[br]) ? wsrc[br][oc * (CC * ksA[br]) + c * ksA[br] + k] : 0.0f;
        wtg[e] = (__bf16)v;
        return;
    }
    // block 0: count -> scan -> fill, all in LDS
    __shared__ int   h[NN];
    __shared__ int   sc[NN];
    __shared__ int   cur[NN];
    __shared__ float dl[NN];
    h[tid] = 0;
    __syncthreads();
    for (int e = tid; e < EE; e += 1024) atomicAdd(&h[ei[EE + e]], 1);
    __syncthreads();
    int v = h[tid];
    sc[tid] = v;
    __syncthreads();
    for (int d = 1; d < NN; d <<= 1) {
        int add = (tid >= d) ? sc[tid - d] : 0;
        __syncthreads();
        sc[tid] += add;
        __syncthreads();
    }
    int oex = sc[tid] - v;
    float dv = rsqrtf((float)v + 1.0f);
    offg[tid] = oex; cntg[tid] = v; dinvg[tid] = dv;
    cur[tid] = oex; dl[tid] = dv;
    __syncthreads();
    for (int e = tid; e < EE; e += 1024) {
        int r = ei[e], c = ei[EE + e];
        int i = atomicAdd(&cur[c], 1);
        src[i] = r;
        wE[i]  = dl[r] * dl[c];
    }
}

// ---------------- fused main: tconv(MFMA) + GCN gather + transform + slin ----------------
// 1 node per block (grid B*N). Wave w owns oc-quadrant w for tconv and o-group w for gcn.

__global__ __launch_bounds__(256) void k_main(
    const float* __restrict__ x, const int* __restrict__ off, const int* __restrict__ cnt,
    const int* __restrict__ src, const float* __restrict__ wE, const float* __restrict__ dinv,
    const __bf16* __restrict__ wtg, const float* __restrict__ bcat,
    const float* __restrict__ wgT, const float* __restrict__ bgp,
    const float* __restrict__ wslT, const float* __restrict__ bsl,
    float* __restrict__ out) {
    __shared__ __align__(16) __bf16 xs[76 * 24];   // bf16 x tile, rows +6 shifted, clamped
    __shared__ float axs[TT * 17];                 // aggregated x [t][c], pad 17
    __shared__ float xlA[TT * OCC];                // transformed [t][o]
    int tid = threadIdx.x;
    int wave = tid >> 6, lane = tid & 63;
    int l15 = lane & 15, g = lane >> 4;
    int b = blockIdx.x >> 10, n = blockIdx.x & (NN - 1);
    size_t bn = blockIdx.x;

    // B-frags for oc-quadrant = wave (6 x bf16x8 = 24 VGPR), L2-hot
    bf16x8 bfr[6];
#pragma unroll
    for (int s = 0; s < 6; s++) {
        const __bf16* p = wtg + (wave * 16 + l15) * 192 + s * 32 + g * 8;
        bfr[s] = __builtin_bit_cast(bf16x8, *(const float4*)p);
    }

    {   // stage tile: f32 -> bf16, rows shifted +6, dup clamp rows 0..5 / 70..75
        const float4* xp = (const float4*)(x + bn * (TT * CC));
        float4 u = xp[tid];
        int t = tid >> 2, c4 = tid & 3;
        uint2 w;
        w.x = pk_bf16(u.x, u.y);
        w.y = pk_bf16(u.z, u.w);
        *(uint2*)(xs + (t + 6) * 24 + c4 * 4) = w;
        if (t == 0) {
#pragma unroll
            for (int r = 0; r < 6; r++) *(uint2*)(xs + r * 24 + c4 * 4) = w;
        }
        if (t == 63) {
#pragma unroll
            for (int r = 70; r < 76; r++) *(uint2*)(xs + r * 24 + c4 * 4) = w;
        }
    }
    __syncthreads();

    // ---- tconv MFMA: C[64t][16oc] for this wave's quadrant, K=192 ----
    float bcol = bcat[wave * 16 + l15];
    f32x4 acc[4];
#pragma unroll
    for (int m = 0; m < 4; m++) acc[m] = (f32x4){bcol, bcol, bcol, bcol};
#pragma unroll
    for (int m = 0; m < 4; m++) {
        bf16x8 a[6];
#pragma unroll
        for (int s = 0; s < 6; s++) {
            const __bf16* p = xs + (m * 16 + l15 + 2 * s + (g >> 1)) * 24 + (g & 1) * 8;
            a[s] = __builtin_bit_cast(bf16x8, *(const float4*)p);
        }
#pragma unroll
        for (int s = 0; s < 6; s++)
            acc[m] = __builtin_amdgcn_mfma_f32_16x16x32_bf16(a[s], bfr[s], acc[m], 0, 0, 0);
    }
    // epilogue: col = l15 (+16*wave), row = m*16 + g*4 + r
#pragma unroll
    for (int m = 0; m < 4; m++) {
        float* op = out + (bn * TT + m * 16 + g * 4) * CHO + wave * 16 + l15;
#pragma unroll
        for (int r = 0; r < 4; r++)
            op[r * CHO] = tanh_fast(acc[m][r]);
    }

    // ---- slin weight row into registers (lane == s), overlaps gather latency ----
    float wv[TT];
#pragma unroll
    for (int t = 0; t < TT; t++) wv[t] = wslT[t * 64 + lane];

    // ---- GCN gather: thread owns 4 consecutive (t,c) words ----
    int o0 = off[n], cn = cnt[n];
    float d = dinv[n], d2 = d * d;
    float4 ag = ((const float4*)(x + bn * (TT * CC)))[tid];
    ag.x *= d2; ag.y *= d2; ag.z *= d2; ag.w *= d2;
    for (int j = 0; j < cn; j++) {
        int s = src[o0 + j];
        float w = wE[o0 + j];
        float4 v = ((const float4*)(x + (size_t)(b * NN + s) * (TT * CC)))[tid];
        ag.x = fmaf(w, v.x, ag.x); ag.y = fmaf(w, v.y, ag.y);
        ag.z = fmaf(w, v.z, ag.z); ag.w = fmaf(w, v.w, ag.w);
    }
    {
        float* w = axs + (tid >> 2) * 17 + (tid & 3) * 4;
        w[0] = ag.x; w[1] = ag.y; w[2] = ag.z; w[3] = ag.w;
    }
    __syncthreads();

    // ---- transform: lane = t, o = wave*4..+3 (weights wave-uniform -> SGPR) ----
    {
        float p4[4];
#pragma unroll
        for (int q = 0; q < 4; q++) p4[q] = bgp[wave * 4 + q];
        const float* ar = axs + lane * 17;
#pragma unroll
        for (int c = 0; c < 16; c++) {
            float xv = ar[c];
#pragma unroll
            for (int q = 0; q < 4; q++)
                p4[q] = fmaf(wgT[c * 16 + wave * 4 + q], xv, p4[q]);
        }
        float4 o;
        o.x = p4[0]; o.y = p4[1]; o.z = p4[2]; o.w = p4[3];
        *(float4*)(xlA + lane * OCC + wave * 4) = o;
    }
    __syncthreads();

    // ---- slin: lane = s, o = wave*4..+3; weights in VGPR, xlA via b128 broadcast ----
    {
        float bv = bsl[lane];
        float a4[4] = {bv, bv, bv, bv};
        const float4* xrow = (const float4*)xlA;
#pragma unroll
        for (int t = 0; t < TT; t++) {
            float4 xv = xrow[t * 4 + wave];    // wave-uniform addr -> broadcast
            a4[0] = fmaf(wv[t], xv.x, a4[0]);
            a4[1] = fmaf(wv[t], xv.y, a4[1]);
            a4[2] = fmaf(wv[t], xv.z, a4[2]);
            a4[3] = fmaf(wv[t], xv.w, a4[3]);
        }
        float4 o;
        o.x = tanh_fast(a4[0]); o.y = tanh_fast(a4[1]);
        o.z = tanh_fast(a4[2]); o.w = tanh_fast(a4[3]);
        *(float4*)(out + (bn * TT + lane) * CHO + 64 + wave * 4) = o;
    }
}

// ---------------- launch ----------------

extern "C" void kernel_launch(void* const* d_in, const int* in_sizes, int n_in,
                              void* d_out, int out_size, void* d_ws, size_t ws_size,
                              hipStream_t stream) {
    const float* x   = (const float*)d_in[0];
    const int*   ei  = (const int*)d_in[1];
    const float* w2  = (const float*)d_in[2];
    const float* b2  = (const float*)d_in[3];
    const float* w3  = (const float*)d_in[4];
    const float* b3  = (const float*)d_in[5];
    const float* w6  = (const float*)d_in[6];
    const float* b6  = (const float*)d_in[7];
    const float* w12 = (const float*)d_in[8];
    const float* b12 = (const float*)d_in[9];
    const float* wg  = (const float*)d_in[10];
    const float* bg  = (const float*)d_in[11];
    const float* wsl = (const float*)d_in[12];
    const float* bsl = (const float*)d_in[13];
    float* out = (float*)d_out;

    // ws layout (bytes): off|cnt|dinv|src|wE|wgT|bgp|bcat|wslT|wtg(bf16)
    char*   ws   = (char*)d_ws;
    int*    off  = (int*)(ws);
    int*    cnt  = (int*)(ws + 4096);
    float*  dinv = (float*)(ws + 8192);
    int*    src  = (int*)(ws + 12288);
    float*  wE   = (float*)(ws + 77824);
    float*  wgT  = (float*)(ws + 143360);
    float*  bgp  = (float*)(ws + 144384);
    float*  bcat = (float*)(ws + 144448);
    float*  wslT = (float*)(ws + 144704);
    __bf16* wtg  = (__bf16*)(ws + 161088);

    k_prep<<<14, 1024, 0, stream>>>(ei, w2, b2, w3, b3, w6, b6, w12, b12, wg, bg, wsl,
                                    off, cnt, dinv, src, wE, wgT, bgp, bcat, wslT, wtg);
    k_main<<<BB * NN, 256, 0, stream>>>(x, off, cnt, src, wE, dinv, wtg, bcat,
                                        wgT, bgp, wslT, bsl, out);
}

// Round 10
// 140.036 us; speedup vs baseline: 1.2384x; 1.2384x over previous
//
#include <hip/hip_runtime.h>
#include <hip/hip_bf16.h>

// Problem constants: B=8, N=1024, T=64, C=16, OC=16, E=16384
#define BB  8
#define NN  1024
#define TT  64
#define CC  16
#define OCC 16
#define EE  16384
#define CHO 80

typedef float  f32x4  __attribute__((ext_vector_type(4)));
typedef __bf16 bf16x8 __attribute__((ext_vector_type(8)));

// fast tanh: tanh(v) = 1 - 2/(e^{2v}+1); inf-safe both ends.
static __device__ __forceinline__ float tanh_fast(float v) {
    float e = __expf(2.0f * v);
    return 1.0f - 2.0f * __builtin_amdgcn_rcpf(e + 1.0f);
}
static __device__ __forceinline__ unsigned pk_bf16(float a, float b) {
    unsigned short lo = __builtin_bit_cast(unsigned short, (__bf16)a);
    unsigned short hi = __builtin_bit_cast(unsigned short, (__bf16)b);
    return (unsigned)lo | ((unsigned)hi << 16);
}

// ---------------- fused prep ----------------
// block 0: graph CSR. blocks 1..12: WTg[64oc][192k] bf16. block 13: wgT, bgp, bcat,
// wsl hi/lo bf16 [s][t].

__global__ __launch_bounds__(1024) void k_prep(
    const int* __restrict__ ei,
    const float* __restrict__ w2,  const float* __restrict__ b2,
    const float* __restrict__ w3,  const float* __restrict__ b3,
    const float* __restrict__ w6,  const float* __restrict__ b6,
    const float* __restrict__ w12, const float* __restrict__ b12,
    const float* __restrict__ wg,  const float* __restrict__ bg,
    const float* __restrict__ wsl,
    int* __restrict__ offg, int* __restrict__ cntg, float* __restrict__ dinvg,
    int* __restrict__ src, float* __restrict__ wE,
    float* __restrict__ wgT, float* __restrict__ bgp, float* __restrict__ bcat,
    __bf16* __restrict__ wslh, __bf16* __restrict__ wsll, __bf16* __restrict__ wtg) {
    int tid = threadIdx.x, bid = blockIdx.x;
    const float* wsrc[4] = {w2, w3, w6, w12};
    const float* bsrc[4] = {b2, b3, b6, b12};
    const int ksA[4] = {2, 3, 6, 12};
    const int plA[4] = {0, 1, 2, 6};
    if (bid == 13) {
        if (tid < 256) wgT[tid] = wg[(tid & 15) * CC + (tid >> 4)];
        else if (tid < 272) bgp[tid - 256] = bg[tid - 256];
        else if (tid < 336) { int j = tid - 272; bcat[j] = bsrc[j >> 4][j & 15]; }
        for (int e = tid; e < 4096; e += 1024) {       // wsl [s][t] hi/lo split
            float v = wsl[e];
            __bf16 h = (__bf16)v;
            wslh[e] = h;
            wsll[e] = (__bf16)(v - (float)h);
        }
        return;
    }
    if (bid != 0) {    // WTg: e in [0, 12288)
        int e = (bid - 1) * 1024 + tid;
        int j = e / 192, kk = e - j * 192;
        int d = kk >> 4, c = kk & 15;
        int br = j >> 4, oc = j & 15;
        int k = d - 6 + plA[br];
        float v = (k >= 0 && k < ksA[br]) ? wsrc[br][oc * (CC * ksA[br]) + c * ksA[br] + k] : 0.0f;
        wtg[e] = (__bf16)v;
        return;
    }
    // block 0: count -> scan -> fill, all in LDS
    __shared__ int   h[NN];
    __shared__ int   sc[NN];
    __shared__ int   cur[NN];
    __shared__ float dl[NN];
    h[tid] = 0;
    __syncthreads();
    for (int e = tid; e < EE; e += 1024) atomicAdd(&h[ei[EE + e]], 1);
    __syncthreads();
    int v = h[tid];
    sc[tid] = v;
    __syncthreads();
    for (int d = 1; d < NN; d <<= 1) {
        int add = (tid >= d) ? sc[tid - d] : 0;
        __syncthreads();
        sc[tid] += add;
        __syncthreads();
    }
    int oex = sc[tid] - v;
    float dv = rsqrtf((float)v + 1.0f);
    offg[tid] = oex; cntg[tid] = v; dinvg[tid] = dv;
    cur[tid] = oex; dl[tid] = dv;
    __syncthreads();
    for (int e = tid; e < EE; e += 1024) {
        int r = ei[e], c = ei[EE + e];
        int i = atomicAdd(&cur[c], 1);
        src[i] = r;
        wE[i]  = dl[r] * dl[c];
    }
}

// ---------------- temporal conv as MFMA GEMM -> out[..., 0:64] ----------------
// 1 node per block; wave owns oc-quadrant. C[64t][16oc] = A[64][192]*B[192][16]+bias.
// A implicit: xs[76 rows][16c] bf16 (rows pre-clamped, stride 24 -> conflict-free b128).
// B: 6 frags/wave from global WTg (L2-hot).

__global__ __launch_bounds__(256) void k_tconv(
    const float* __restrict__ x, const __bf16* __restrict__ wtg,
    const float* __restrict__ bcat, float* __restrict__ out) {
    __shared__ __align__(16) __bf16 xs[76 * 24];
    int tid = threadIdx.x;
    int wave = tid >> 6, lane = tid & 63;
    int l15 = lane & 15, g = lane >> 4;
    size_t bn = blockIdx.x;

    bf16x8 bfr[6];
#pragma unroll
    for (int s = 0; s < 6; s++) {
        const __bf16* p = wtg + (wave * 16 + l15) * 192 + s * 32 + g * 8;
        bfr[s] = __builtin_bit_cast(bf16x8, *(const float4*)p);
    }

    {   // stage tile: f32 -> bf16, rows +6 shifted, dup clamp rows 0..5 / 70..75
        const float4* xp = (const float4*)(x + bn * (TT * CC));
        float4 u = xp[tid];
        int t = tid >> 2, c4 = tid & 3;
        uint2 w;
        w.x = pk_bf16(u.x, u.y);
        w.y = pk_bf16(u.z, u.w);
        *(uint2*)(xs + (t + 6) * 24 + c4 * 4) = w;
        if (t == 0) {
#pragma unroll
            for (int r = 0; r < 6; r++) *(uint2*)(xs + r * 24 + c4 * 4) = w;
        }
        if (t == 63) {
#pragma unroll
            for (int r = 70; r < 76; r++) *(uint2*)(xs + r * 24 + c4 * 4) = w;
        }
    }
    __syncthreads();

    float bcol = bcat[wave * 16 + l15];
    f32x4 acc[4];
#pragma unroll
    for (int m = 0; m < 4; m++) acc[m] = (f32x4){bcol, bcol, bcol, bcol};
#pragma unroll
    for (int m = 0; m < 4; m++) {
        bf16x8 a[6];
#pragma unroll
        for (int s = 0; s < 6; s++) {
            const __bf16* p = xs + (m * 16 + l15 + 2 * s + (g >> 1)) * 24 + (g & 1) * 8;
            a[s] = __builtin_bit_cast(bf16x8, *(const float4*)p);
        }
#pragma unroll
        for (int s = 0; s < 6; s++)
            acc[m] = __builtin_amdgcn_mfma_f32_16x16x32_bf16(a[s], bfr[s], acc[m], 0, 0, 0);
    }
    // C layout: col = l15 (+16*wave), row = m*16 + g*4 + r
#pragma unroll
    for (int m = 0; m < 4; m++) {
        float* op = out + (bn * TT + m * 16 + g * 4) * CHO + wave * 16 + l15;
#pragma unroll
        for (int r = 0; r < 4; r++)
            op[r * CHO] = tanh_fast(acc[m][r]);
    }
}

// ---------------- GCN: CSR gather + transform (f32) + slin via hi/lo MFMA ----------------
// slin: C[16o][64s] = xlA^T[16o][64t] * wsl^T[64t][64s]; wave = s-quadrant, 2 k-steps.
// hi/lo bf16 split on both operands keeps slin effectively f32.

__global__ __launch_bounds__(256) void k_gcn(
    const float* __restrict__ x, const int* __restrict__ off, const int* __restrict__ cnt,
    const int* __restrict__ src, const float* __restrict__ wE, const float* __restrict__ dinv,
    const float* __restrict__ wgT, const float* __restrict__ bgp,
    const __bf16* __restrict__ wslh, const __bf16* __restrict__ wsll,
    const float* __restrict__ bsl, float* __restrict__ out) {
    __shared__ float axs[TT * 17];                   // aggregated x [t][c], pad 17
    __shared__ __align__(16) __bf16 xh[16 * 72];     // xlA^T hi [o][t], row 72 (144B, 16B-mult)
    __shared__ __align__(16) __bf16 xl2[16 * 72];    // xlA^T lo
    int tid = threadIdx.x;
    int wave = tid >> 6, lane = tid & 63;
    int l15 = lane & 15, g = lane >> 4;
    int b = blockIdx.x >> 10, n = blockIdx.x & (NN - 1);
    size_t bn = blockIdx.x;

    // slin B-frags (wave-quadrant of wsl, L2-hot): lane l15 = s_local; k-chunk = kstep*32+g*8
    int sglob = wave * 16 + l15;
    bf16x8 bh[2], bl[2];
#pragma unroll
    for (int k = 0; k < 2; k++) {
        bh[k] = __builtin_bit_cast(bf16x8, *(const float4*)(wslh + sglob * 64 + k * 32 + g * 8));
        bl[k] = __builtin_bit_cast(bf16x8, *(const float4*)(wsll + sglob * 64 + k * 32 + g * 8));
    }

    // ---- aggregate neighbors (thread owns 4 consecutive (t,c) words) ----
    int o0 = off[n], cn = cnt[n];
    float d = dinv[n], d2 = d * d;
    float4 ag = ((const float4*)(x + bn * (TT * CC)))[tid];
    ag.x *= d2; ag.y *= d2; ag.z *= d2; ag.w *= d2;
    for (int j = 0; j < cn; j++) {
        int s = src[o0 + j];
        float w = wE[o0 + j];
        float4 v = ((const float4*)(x + (size_t)(b * NN + s) * (TT * CC)))[tid];
        ag.x = fmaf(w, v.x, ag.x); ag.y = fmaf(w, v.y, ag.y);
        ag.z = fmaf(w, v.z, ag.z); ag.w = fmaf(w, v.w, ag.w);
    }
    {
        float* w = axs + (tid >> 2) * 17 + (tid & 3) * 4;
        w[0] = ag.x; w[1] = ag.y; w[2] = ag.z; w[3] = ag.w;
    }
    __syncthreads();

    // ---- transform (f32): lane = t, o = wave*4..+3; write xlA^T hi/lo bf16 ----
    {
        float p4[4];
#pragma unroll
        for (int q = 0; q < 4; q++) p4[q] = bgp[wave * 4 + q];
        const float* ar = axs + lane * 17;
#pragma unroll
        for (int c = 0; c < 16; c++) {
            float xv = ar[c];
#pragma unroll
            for (int q = 0; q < 4; q++)
                p4[q] = fmaf(wgT[c * 16 + wave * 4 + q], xv, p4[q]);
        }
#pragma unroll
        for (int q = 0; q < 4; q++) {
            int o = wave * 4 + q;
            __bf16 h = (__bf16)p4[q];
            xh[o * 72 + lane]  = h;
            xl2[o * 72 + lane] = (__bf16)(p4[q] - (float)h);
        }
    }
    __syncthreads();

    // ---- slin MFMA: A lane l15 = o, k-chunk = kstep*32 + g*8 ----
    {
        float bv = bsl[sglob];
        f32x4 acc = (f32x4){bv, bv, bv, bv};
        bf16x8 ah[2], al[2];
#pragma unroll
        for (int k = 0; k < 2; k++) {
            ah[k] = __builtin_bit_cast(bf16x8, *(const float4*)(xh  + l15 * 72 + k * 32 + g * 8));
            al[k] = __builtin_bit_cast(bf16x8, *(const float4*)(xl2 + l15 * 72 + k * 32 + g * 8));
        }
#pragma unroll
        for (int k = 0; k < 2; k++) {
            acc = __builtin_amdgcn_mfma_f32_16x16x32_bf16(ah[k], bh[k], acc, 0, 0, 0);
            acc = __builtin_amdgcn_mfma_f32_16x16x32_bf16(al[k], bh[k], acc, 0, 0, 0);
            acc = __builtin_amdgcn_mfma_f32_16x16x32_bf16(ah[k], bl[k], acc, 0, 0, 0);
        }
        // C: col = l15 -> s_local (sglob row of out), row = g*4+r -> o
        float4 o4;
        o4.x = tanh_fast(acc[0]); o4.y = tanh_fast(acc[1]);
        o4.z = tanh_fast(acc[2]); o4.w = tanh_fast(acc[3]);
        *(float4*)(out + (bn * TT + sglob) * CHO + 64 + g * 4) = o4;
    }
}

// ---------------- launch ----------------

extern "C" void kernel_launch(void* const* d_in, const int* in_sizes, int n_in,
                              void* d_out, int out_size, void* d_ws, size_t ws_size,
                              hipStream_t stream) {
    const float* x   = (const float*)d_in[0];
    const int*   ei  = (const int*)d_in[1];
    const float* w2  = (const float*)d_in[2];
    const float* b2  = (const float*)d_in[3];
    const float* w3  = (const float*)d_in[4];
    const float* b3  = (const float*)d_in[5];
    const float* w6  = (const float*)d_in[6];
    const float* b6  = (const float*)d_in[7];
    const float* w12 = (const float*)d_in[8];
    const float* b12 = (const float*)d_in[9];
    const float* wg  = (const float*)d_in[10];
    const float* bg  = (const float*)d_in[11];
    const float* wsl = (const float*)d_in[12];
    const float* bsl = (const float*)d_in[13];
    float* out = (float*)d_out;

    // ws layout (bytes): off|cnt|dinv|src|wE|wgT|bgp|bcat|wslh|wsll|wtg
    char*   ws   = (char*)d_ws;
    int*    off  = (int*)(ws);
    int*    cnt  = (int*)(ws + 4096);
    float*  dinv = (float*)(ws + 8192);
    int*    src  = (int*)(ws + 12288);
    float*  wE   = (float*)(ws + 77824);
    float*  wgT  = (float*)(ws + 143360);
    float*  bgp  = (float*)(ws + 144384);
    float*  bcat = (float*)(ws + 144448);
    __bf16* wslh = (__bf16*)(ws + 144704);
    __bf16* wsll = (__bf16*)(ws + 152896);
    __bf16* wtg  = (__bf16*)(ws + 161088);

    k_prep<<<14, 1024, 0, stream>>>(ei, w2, b2, w3, b3, w6, b6, w12, b12, wg, bg, wsl,
                                    off, cnt, dinv, src, wE, wgT, bgp, bcat, wslh, wsll, wtg);
    k_tconv<<<BB * NN, 256, 0, stream>>>(x, wtg, bcat, out);
    k_gcn<<<BB * NN, 256, 0, stream>>>(x, off, cnt, src, wE, dinv, wgT, bgp,
                                       wslh, wsll, bsl, out);
}

// Round 11
// 131.883 us; speedup vs baseline: 1.3150x; 1.0618x over previous
//
#include <hip/hip_runtime.h>
#include <hip/hip_bf16.h>

// Problem constants: B=8, N=1024, T=64, C=16, OC=16, E=16384
#define BB  8
#define NN  1024
#define TT  64
#define CC  16
#define OCC 16
#define EE  16384
#define CHO 80

typedef float  f32x4  __attribute__((ext_vector_type(4)));
typedef __bf16 bf16x8 __attribute__((ext_vector_type(8)));

// fast tanh: tanh(v) = 1 - 2/(e^{2v}+1); inf-safe both ends.
static __device__ __forceinline__ float tanh_fast(float v) {
    float e = __expf(2.0f * v);
    return 1.0f - 2.0f * __builtin_amdgcn_rcpf(e + 1.0f);
}
static __device__ __forceinline__ unsigned pk_bf16(float a, float b) {
    unsigned short lo = __builtin_bit_cast(unsigned short, (__bf16)a);
    unsigned short hi = __builtin_bit_cast(unsigned short, (__bf16)b);
    return (unsigned)lo | ((unsigned)hi << 16);
}
static __device__ __forceinline__ float bflo(unsigned u) { return __uint_as_float(u << 16); }
static __device__ __forceinline__ float bfhi(unsigned u) { return __uint_as_float(u & 0xFFFF0000u); }

// ---------------- fused prep ----------------
// bid 0: graph CSR. 1..12: WTg[64oc][192k] bf16. 13: wgT, bgp, bcat, wsl hi/lo.
// 14..2061: x -> bf16 (xb).

__global__ __launch_bounds__(1024) void k_prep(
    const int* __restrict__ ei, const float* __restrict__ x,
    const float* __restrict__ w2,  const float* __restrict__ b2,
    const float* __restrict__ w3,  const float* __restrict__ b3,
    const float* __restrict__ w6,  const float* __restrict__ b6,
    const float* __restrict__ w12, const float* __restrict__ b12,
    const float* __restrict__ wg,  const float* __restrict__ bg,
    const float* __restrict__ wsl,
    int* __restrict__ offg, int* __restrict__ cntg, float* __restrict__ dinvg,
    int* __restrict__ src, float* __restrict__ wE,
    float* __restrict__ wgT, float* __restrict__ bgp, float* __restrict__ bcat,
    __bf16* __restrict__ wslh, __bf16* __restrict__ wsll, __bf16* __restrict__ wtg,
    __bf16* __restrict__ xb) {
    int tid = threadIdx.x, bid = blockIdx.x;
    const float* wsrc[4] = {w2, w3, w6, w12};
    const float* bsrc[4] = {b2, b3, b6, b12};
    const int ksA[4] = {2, 3, 6, 12};
    const int plA[4] = {0, 1, 2, 6};
    if (bid >= 14) {    // x -> bf16, 4 elems/thread
        int e4 = (bid - 14) * 1024 + tid;     // float4 index, 2048*1024 total = exact
        float4 u = ((const float4*)x)[e4];
        uint2 w;
        w.x = pk_bf16(u.x, u.y);
        w.y = pk_bf16(u.z, u.w);
        ((uint2*)xb)[e4] = w;
        return;
    }
    if (bid == 13) {
        if (tid < 256) wgT[tid] = wg[(tid & 15) * CC + (tid >> 4)];
        else if (tid < 272) bgp[tid - 256] = bg[tid - 256];
        else if (tid < 336) { int j = tid - 272; bcat[j] = bsrc[j >> 4][j & 15]; }
        for (int e = tid; e < 4096; e += 1024) {       // wsl [s][t] hi/lo split
            float v = wsl[e];
            __bf16 h = (__bf16)v;
            wslh[e] = h;
            wsll[e] = (__bf16)(v - (float)h);
        }
        return;
    }
    if (bid != 0) {    // WTg: e in [0, 12288)
        int e = (bid - 1) * 1024 + tid;
        int j = e / 192, kk = e - j * 192;
        int d = kk >> 4, c = kk & 15;
        int br = j >> 4, oc = j & 15;
        int k = d - 6 + plA[br];
        float v = (k >= 0 && k < ksA[br]) ? wsrc[br][oc * (CC * ksA[br]) + c * ksA[br] + k] : 0.0f;
        wtg[e] = (__bf16)v;
        return;
    }
    // block 0: count -> scan -> fill, all in LDS
    __shared__ int   h[NN];
    __shared__ int   sc[NN];
    __shared__ int   cur[NN];
    __shared__ float dl[NN];
    h[tid] = 0;
    __syncthreads();
    for (int e = tid; e < EE; e += 1024) atomicAdd(&h[ei[EE + e]], 1);
    __syncthreads();
    int v = h[tid];
    sc[tid] = v;
    __syncthreads();
    for (int d = 1; d < NN; d <<= 1) {
        int add = (tid >= d) ? sc[tid - d] : 0;
        __syncthreads();
        sc[tid] += add;
        __syncthreads();
    }
    int oex = sc[tid] - v;
    float dv = rsqrtf((float)v + 1.0f);
    offg[tid] = oex; cntg[tid] = v; dinvg[tid] = dv;
    cur[tid] = oex; dl[tid] = dv;
    __syncthreads();
    for (int e = tid; e < EE; e += 1024) {
        int r = ei[e], c = ei[EE + e];
        int i = atomicAdd(&cur[c], 1);
        src[i] = r;
        wE[i]  = dl[r] * dl[c];
    }
}

// ---------------- temporal conv MFMA -> out[..., 0:64] ----------------
// 4 nodes per block (grid 2048); wave = m-quadrant (rows wave*16..+15): A-frags private
// (6/wave/node from LDS), B = all 24 frags in VGPR loaded once (L1-hot), 1 sync total.
// XCD swizzle: b = blk&7, node-quad = blk>>3.

__global__ __launch_bounds__(256) void k_tconv(
    const __bf16* __restrict__ xb, const __bf16* __restrict__ wtg,
    const float* __restrict__ bcat, float* __restrict__ out) {
    __shared__ __align__(16) __bf16 xs[4][76 * 24];   // rows +6 shifted, clamped, stride 24
    int tid = threadIdx.x;
    int wave = tid >> 6, lane = tid & 63;
    int l15 = lane & 15, g = lane >> 4;
    int bq = blockIdx.x & 7, nq = blockIdx.x >> 3;    // batch, node-quad

    // all 24 B-frags (96 VGPR): bfr[s][n]
    bf16x8 bfr[6][4];
#pragma unroll
    for (int s = 0; s < 6; s++)
#pragma unroll
        for (int n = 0; n < 4; n++) {
            const __bf16* p = wtg + (n * 16 + l15) * 192 + s * 32 + g * 8;
            bfr[s][n] = __builtin_bit_cast(bf16x8, *(const float4*)p);
        }
    float bcol[4];
#pragma unroll
    for (int n = 0; n < 4; n++) bcol[n] = bcat[n * 16 + l15];

    {   // stage all 4 node tiles (bf16 source, uint2 = 4 elems per thread per node)
        int t = tid >> 2, c0 = (tid & 3) * 4;
#pragma unroll
        for (int node = 0; node < 4; node++) {
            size_t bn = (size_t)bq * NN + nq * 4 + node;
            uint2 w = *(const uint2*)(xb + bn * (TT * CC) + tid * 4);
            *(uint2*)(xs[node] + (t + 6) * 24 + c0) = w;
            if (t == 0) {
#pragma unroll
                for (int r = 0; r < 6; r++) *(uint2*)(xs[node] + r * 24 + c0) = w;
            }
            if (t == 63) {
#pragma unroll
                for (int r = 70; r < 76; r++) *(uint2*)(xs[node] + r * 24 + c0) = w;
            }
        }
    }
    __syncthreads();

    for (int node = 0; node < 4; node++) {
        size_t bn = (size_t)bq * NN + nq * 4 + node;
        f32x4 acc[4];
#pragma unroll
        for (int n = 0; n < 4; n++) acc[n] = (f32x4){bcol[n], bcol[n], bcol[n], bcol[n]};
#pragma unroll
        for (int s = 0; s < 6; s++) {
            // A-frag for this wave's m: row = wave*16 + l15 + 2s + (g>>1), half = (g&1)*8
            const __bf16* p = xs[node] + (wave * 16 + l15 + 2 * s + (g >> 1)) * 24 + (g & 1) * 8;
            bf16x8 a = __builtin_bit_cast(bf16x8, *(const float4*)p);
#pragma unroll
            for (int n = 0; n < 4; n++)
                acc[n] = __builtin_amdgcn_mfma_f32_16x16x32_bf16(a, bfr[s][n], acc[n], 0, 0, 0);
        }
        // C: row = wave*16 + g*4 + r, col = n*16 + l15
        float* op = out + (bn * TT + wave * 16 + g * 4) * CHO + l15;
#pragma unroll
        for (int r = 0; r < 4; r++)
#pragma unroll
            for (int n = 0; n < 4; n++)
                op[r * CHO + n * 16] = tanh_fast(acc[n][r]);
    }
}

// ---------------- GCN: bf16 CSR gather (XCD-local) + transform f32 + slin hi/lo MFMA ----

__global__ __launch_bounds__(256) void k_gcn(
    const float* __restrict__ x, const __bf16* __restrict__ xb,
    const int* __restrict__ off, const int* __restrict__ cnt,
    const int* __restrict__ src, const float* __restrict__ wE, const float* __restrict__ dinv,
    const float* __restrict__ wgT, const float* __restrict__ bgp,
    const __bf16* __restrict__ wslh, const __bf16* __restrict__ wsll,
    const float* __restrict__ bsl, float* __restrict__ out) {
    __shared__ float axs[TT * 17];                   // aggregated x [t][c], pad 17
    __shared__ __align__(16) __bf16 xh[16 * 72];     // xlA^T hi [o][t]
    __shared__ __align__(16) __bf16 xl2[16 * 72];    // xlA^T lo
    int tid = threadIdx.x;
    int wave = tid >> 6, lane = tid & 63;
    int l15 = lane & 15, g = lane >> 4;
    int b = blockIdx.x & 7, n = blockIdx.x >> 3;     // XCD swizzle: batch = blk & 7
    size_t bn = (size_t)b * NN + n;

    // slin B-frags (wave-quadrant of wsl, L2-hot)
    int sglob = wave * 16 + l15;
    bf16x8 bh[2], bl[2];
#pragma unroll
    for (int k = 0; k < 2; k++) {
        bh[k] = __builtin_bit_cast(bf16x8, *(const float4*)(wslh + sglob * 64 + k * 32 + g * 8));
        bl[k] = __builtin_bit_cast(bf16x8, *(const float4*)(wsll + sglob * 64 + k * 32 + g * 8));
    }

    // ---- aggregate: self in f32 (exact), neighbors from bf16 xb (4 elems/thread) ----
    int o0 = off[n], cn = cnt[n];
    float d = dinv[n], d2 = d * d;
    float4 sf = ((const float4*)(x + bn * (TT * CC)))[tid];
    float a0 = d2 * sf.x, a1 = d2 * sf.y, a2 = d2 * sf.z, a3 = d2 * sf.w;
    const __bf16* xbb = xb + (size_t)b * NN * (TT * CC) + tid * 4;
    const int* srcp = src + o0;
    const float* wEp = wE + o0;
    int j = 0;
    for (; j + 4 <= cn; j += 4) {
        int s0 = srcp[j], s1 = srcp[j + 1], s2 = srcp[j + 2], s3 = srcp[j + 3];
        float w0 = wEp[j], w1 = wEp[j + 1], w2 = wEp[j + 2], w3 = wEp[j + 3];
        uint2 v0 = *(const uint2*)(xbb + (size_t)s0 * (TT * CC));
        uint2 v1 = *(const uint2*)(xbb + (size_t)s1 * (TT * CC));
        uint2 v2 = *(const uint2*)(xbb + (size_t)s2 * (TT * CC));
        uint2 v3 = *(const uint2*)(xbb + (size_t)s3 * (TT * CC));
        a0 = fmaf(w0, bflo(v0.x), fmaf(w1, bflo(v1.x), fmaf(w2, bflo(v2.x), fmaf(w3, bflo(v3.x), a0))));
        a1 = fmaf(w0, bfhi(v0.x), fmaf(w1, bfhi(v1.x), fmaf(w2, bfhi(v2.x), fmaf(w3, bfhi(v3.x), a1))));
        a2 = fmaf(w0, bflo(v0.y), fmaf(w1, bflo(v1.y), fmaf(w2, bflo(v2.y), fmaf(w3, bflo(v3.y), a2))));
        a3 = fmaf(w0, bfhi(v0.y), fmaf(w1, bfhi(v1.y), fmaf(w2, bfhi(v2.y), fmaf(w3, bfhi(v3.y), a3))));
    }
    for (; j < cn; j++) {
        int s = srcp[j];
        float w = wEp[j];
        uint2 v = *(const uint2*)(xbb + (size_t)s * (TT * CC));
        a0 = fmaf(w, bflo(v.x), a0); a1 = fmaf(w, bfhi(v.x), a1);
        a2 = fmaf(w, bflo(v.y), a2); a3 = fmaf(w, bfhi(v.y), a3);
    }
    {
        float* w = axs + (tid >> 2) * 17 + (tid & 3) * 4;
        w[0] = a0; w[1] = a1; w[2] = a2; w[3] = a3;
    }
    __syncthreads();

    // ---- transform (f32): lane = t, o = wave*4..+3; write xlA^T hi/lo bf16 ----
    {
        float p4[4];
#pragma unroll
        for (int q = 0; q < 4; q++) p4[q] = bgp[wave * 4 + q];
        const float* ar = axs + lane * 17;
#pragma unroll
        for (int c = 0; c < 16; c++) {
            float xv = ar[c];
#pragma unroll
            for (int q = 0; q < 4; q++)
                p4[q] = fmaf(wgT[c * 16 + wave * 4 + q], xv, p4[q]);
        }
#pragma unroll
        for (int q = 0; q < 4; q++) {
            int o = wave * 4 + q;
            __bf16 h = (__bf16)p4[q];
            xh[o * 72 + lane]  = h;
            xl2[o * 72 + lane] = (__bf16)(p4[q] - (float)h);
        }
    }
    __syncthreads();

    // ---- slin MFMA hi/lo: A lane l15 = o, k-chunk = kstep*32 + g*8 ----
    {
        float bv = bsl[sglob];
        f32x4 acc = (f32x4){bv, bv, bv, bv};
        bf16x8 ah[2], al[2];
#pragma unroll
        for (int k = 0; k < 2; k++) {
            ah[k] = __builtin_bit_cast(bf16x8, *(const float4*)(xh  + l15 * 72 + k * 32 + g * 8));
            al[k] = __builtin_bit_cast(bf16x8, *(const float4*)(xl2 + l15 * 72 + k * 32 + g * 8));
        }
#pragma unroll
        for (int k = 0; k < 2; k++) {
            acc = __builtin_amdgcn_mfma_f32_16x16x32_bf16(ah[k], bh[k], acc, 0, 0, 0);
            acc = __builtin_amdgcn_mfma_f32_16x16x32_bf16(al[k], bh[k], acc, 0, 0, 0);
            acc = __builtin_amdgcn_mfma_f32_16x16x32_bf16(ah[k], bl[k], acc, 0, 0, 0);
        }
        float4 o4;
        o4.x = tanh_fast(acc[0]); o4.y = tanh_fast(acc[1]);
        o4.z = tanh_fast(acc[2]); o4.w = tanh_fast(acc[3]);
        *(float4*)(out + (bn * TT + sglob) * CHO + 64 + g * 4) = o4;
    }
}

// ---------------- launch ----------------

extern "C" void kernel_launch(void* const* d_in, const int* in_sizes, int n_in,
                              void* d_out, int out_size, void* d_ws, size_t ws_size,
                              hipStream_t stream) {
    const float* x   = (const float*)d_in[0];
    const int*   ei  = (const int*)d_in[1];
    const float* w2  = (const float*)d_in[2];
    const float* b2  = (const float*)d_in[3];
    const float* w3  = (const float*)d_in[4];
    const float* b3  = (const float*)d_in[5];
    const float* w6  = (const float*)d_in[6];
    const float* b6  = (const float*)d_in[7];
    const float* w12 = (const float*)d_in[8];
    const float* b12 = (const float*)d_in[9];
    const float* wg  = (const float*)d_in[10];
    const float* bg  = (const float*)d_in[11];
    const float* wsl = (const float*)d_in[12];
    const float* bsl = (const float*)d_in[13];
    float* out = (float*)d_out;

    // ws layout (bytes): off|cnt|dinv|src|wE|wgT|bgp|bcat|wslh|wsll|wtg ... xb @4MB
    char*   ws   = (char*)d_ws;
    int*    off  = (int*)(ws);
    int*    cnt  = (int*)(ws + 4096);
    float*  dinv = (float*)(ws + 8192);
    int*    src  = (int*)(ws + 12288);
    float*  wE   = (float*)(ws + 77824);
    float*  wgT  = (float*)(ws + 143360);
    float*  bgp  = (float*)(ws + 144384);
    float*  bcat = (float*)(ws + 144448);
    __bf16* wslh = (__bf16*)(ws + 144704);
    __bf16* wsll = (__bf16*)(ws + 152896);
    __bf16* wtg  = (__bf16*)(ws + 161088);
    __bf16* xb   = (__bf16*)(ws + 4194304);

    k_prep<<<2062, 1024, 0, stream>>>(ei, x, w2, b2, w3, b3, w6, b6, w12, b12, wg, bg, wsl,
                                      off, cnt, dinv, src, wE, wgT, bgp, bcat,
                                      wslh, wsll, wtg, xb);
    k_tconv<<<BB * NN / 4, 256, 0, stream>>>(xb, wtg, bcat, out);
    k_gcn<<<BB * NN, 256, 0, stream>>>(x, xb, off, cnt, src, wE, dinv, wgT, bgp,
                                       wslh, wsll, bsl, out);
}

// Round 12
// 122.959 us; speedup vs baseline: 1.4104x; 1.0726x over previous
//
#include <hip/hip_runtime.h>
#include <hip/hip_bf16.h>

// Problem constants: B=8, N=1024, T=64, C=16, OC=16, E=16384
#define BB  8
#define NN  1024
#define TT  64
#define CC  16
#define OCC 16
#define EE  16384
#define CHO 80

typedef float  f32x4  __attribute__((ext_vector_type(4)));
typedef __bf16 bf16x8 __attribute__((ext_vector_type(8)));

// fast tanh: tanh(v) = 1 - 2/(e^{2v}+1); inf-safe both ends.
static __device__ __forceinline__ float tanh_fast(float v) {
    float e = __expf(2.0f * v);
    return 1.0f - 2.0f * __builtin_amdgcn_rcpf(e + 1.0f);
}
static __device__ __forceinline__ unsigned pk_bf16(float a, float b) {
    unsigned short lo = __builtin_bit_cast(unsigned short, (__bf16)a);
    unsigned short hi = __builtin_bit_cast(unsigned short, (__bf16)b);
    return (unsigned)lo | ((unsigned)hi << 16);
}
static __device__ __forceinline__ float bflo(unsigned u) { return __uint_as_float(u << 16); }
static __device__ __forceinline__ float bfhi(unsigned u) { return __uint_as_float(u & 0xFFFF0000u); }

// ---------------- fused prep ----------------
// bid 0: graph CSR. 1..12: WTg[64oc][192k] bf16. 13: wgT, bgp, bcat, wsl hi/lo.
// 14..2061: x -> bf16 (xb).

__global__ __launch_bounds__(1024) void k_prep(
    const int* __restrict__ ei, const float* __restrict__ x,
    const float* __restrict__ w2,  const float* __restrict__ b2,
    const float* __restrict__ w3,  const float* __restrict__ b3,
    const float* __restrict__ w6,  const float* __restrict__ b6,
    const float* __restrict__ w12, const float* __restrict__ b12,
    const float* __restrict__ wg,  const float* __restrict__ bg,
    const float* __restrict__ wsl,
    int* __restrict__ offg, int* __restrict__ cntg, float* __restrict__ dinvg,
    int* __restrict__ src, float* __restrict__ wE,
    float* __restrict__ wgT, float* __restrict__ bgp, float* __restrict__ bcat,
    __bf16* __restrict__ wslh, __bf16* __restrict__ wsll, __bf16* __restrict__ wtg,
    __bf16* __restrict__ xb) {
    int tid = threadIdx.x, bid = blockIdx.x;
    const float* wsrc[4] = {w2, w3, w6, w12};
    const float* bsrc[4] = {b2, b3, b6, b12};
    const int ksA[4] = {2, 3, 6, 12};
    const int plA[4] = {0, 1, 2, 6};
    if (bid >= 14) {    // x -> bf16, 4 elems/thread
        int e4 = (bid - 14) * 1024 + tid;     // float4 index, 2048*1024 total = exact
        float4 u = ((const float4*)x)[e4];
        uint2 w;
        w.x = pk_bf16(u.x, u.y);
        w.y = pk_bf16(u.z, u.w);
        ((uint2*)xb)[e4] = w;
        return;
    }
    if (bid == 13) {
        if (tid < 256) wgT[tid] = wg[(tid & 15) * CC + (tid >> 4)];
        else if (tid < 272) bgp[tid - 256] = bg[tid - 256];
        else if (tid < 336) { int j = tid - 272; bcat[j] = bsrc[j >> 4][j & 15]; }
        for (int e = tid; e < 4096; e += 1024) {       // wsl [s][t] hi/lo split
            float v = wsl[e];
            __bf16 h = (__bf16)v;
            wslh[e] = h;
            wsll[e] = (__bf16)(v - (float)h);
        }
        return;
    }
    if (bid != 0) {    // WTg: e in [0, 12288)
        int e = (bid - 1) * 1024 + tid;
        int j = e / 192, kk = e - j * 192;
        int d = kk >> 4, c = kk & 15;
        int br = j >> 4, oc = j & 15;
        int k = d - 6 + plA[br];
        float v = (k >= 0 && k < ksA[br]) ? wsrc[br][oc * (CC * ksA[br]) + c * ksA[br] + k] : 0.0f;
        wtg[e] = (__bf16)v;
        return;
    }
    // block 0: count -> scan -> fill, all in LDS
    __shared__ int   h[NN];
    __shared__ int   sc[NN];
    __shared__ int   cur[NN];
    __shared__ float dl[NN];
    h[tid] = 0;
    __syncthreads();
    for (int e = tid; e < EE; e += 1024) atomicAdd(&h[ei[EE + e]], 1);
    __syncthreads();
    int v = h[tid];
    sc[tid] = v;
    __syncthreads();
    for (int d = 1; d < NN; d <<= 1) {
        int add = (tid >= d) ? sc[tid - d] : 0;
        __syncthreads();
        sc[tid] += add;
        __syncthreads();
    }
    int oex = sc[tid] - v;
    float dv = rsqrtf((float)v + 1.0f);
    offg[tid] = oex; cntg[tid] = v; dinvg[tid] = dv;
    cur[tid] = oex; dl[tid] = dv;
    __syncthreads();
    for (int e = tid; e < EE; e += 1024) {
        int r = ei[e], c = ei[EE + e];
        int i = atomicAdd(&cur[c], 1);
        src[i] = r;
        wE[i]  = dl[r] * dl[c];
    }
}

// ---------------- temporal conv MFMA (swapped operands) -> out[..., 0:64] ----------------
// 4 nodes per block; wave = oc-block w: A-frags = weights (l15 = oc row, loaded ONCE),
// B-frags = x from LDS (l15 = t col). C^T: lane l15 = t, rows oc = w*16+g*4+r ->
// one float4 store per (m,node): 4 b128 stores/node vs 64 scalar (16x fewer).

__global__ __launch_bounds__(256) void k_tconv(
    const __bf16* __restrict__ xb, const __bf16* __restrict__ wtg,
    const float* __restrict__ bcat, float* __restrict__ out) {
    __shared__ __align__(16) __bf16 xs[4][76 * 24];   // rows +6 shifted, clamped, stride 24
    int tid = threadIdx.x;
    int wave = tid >> 6, lane = tid & 63;
    int l15 = lane & 15, g = lane >> 4;
    int bq = blockIdx.x & 7, nq = blockIdx.x >> 3;    // batch, node-quad

    // A-frags: weights for oc-rows wave*16 + l15 (6 frags = 24 VGPR, loaded once)
    bf16x8 afr[6];
#pragma unroll
    for (int s = 0; s < 6; s++) {
        const __bf16* p = wtg + (wave * 16 + l15) * 192 + s * 32 + g * 8;
        afr[s] = __builtin_bit_cast(bf16x8, *(const float4*)p);
    }
    // bias for rows oc = wave*16 + g*4 + r
    float4 bias = *(const float4*)(bcat + wave * 16 + g * 4);

    {   // stage all 4 node tiles (bf16 source, uint2 = 4 elems per thread per node)
        int t = tid >> 2, c0 = (tid & 3) * 4;
#pragma unroll
        for (int node = 0; node < 4; node++) {
            size_t bn = (size_t)bq * NN + nq * 4 + node;
            uint2 w = *(const uint2*)(xb + bn * (TT * CC) + tid * 4);
            *(uint2*)(xs[node] + (t + 6) * 24 + c0) = w;
            if (t == 0) {
#pragma unroll
                for (int r = 0; r < 6; r++) *(uint2*)(xs[node] + r * 24 + c0) = w;
            }
            if (t == 63) {
#pragma unroll
                for (int r = 70; r < 76; r++) *(uint2*)(xs[node] + r * 24 + c0) = w;
            }
        }
    }
    __syncthreads();

    for (int node = 0; node < 4; node++) {
        size_t bn = (size_t)bq * NN + nq * 4 + node;
        f32x4 acc[4];
#pragma unroll
        for (int m = 0; m < 4; m++) acc[m] = (f32x4){bias.x, bias.y, bias.z, bias.w};
#pragma unroll
        for (int m = 0; m < 4; m++) {
#pragma unroll
            for (int s = 0; s < 6; s++) {
                // B-frag (x): col t = m*16 + l15, k-row = 2s + (g>>1), c-half = g&1
                const __bf16* p = xs[node] + (m * 16 + l15 + 2 * s + (g >> 1)) * 24 + (g & 1) * 8;
                bf16x8 b = __builtin_bit_cast(bf16x8, *(const float4*)p);
                acc[m] = __builtin_amdgcn_mfma_f32_16x16x32_bf16(afr[s], b, acc[m], 0, 0, 0);
            }
        }
        // C^T: col = l15 -> t, row = g*4 + r -> oc; float4 store per m
#pragma unroll
        for (int m = 0; m < 4; m++) {
            float4 o;
            o.x = tanh_fast(acc[m][0]); o.y = tanh_fast(acc[m][1]);
            o.z = tanh_fast(acc[m][2]); o.w = tanh_fast(acc[m][3]);
            *(float4*)(out + (bn * TT + m * 16 + l15) * CHO + wave * 16 + g * 4) = o;
        }
    }
}

// ---------------- GCN: bf16 CSR gather (XCD-local) + transform f32 + slin hi/lo MFMA ----

__global__ __launch_bounds__(256) void k_gcn(
    const float* __restrict__ x, const __bf16* __restrict__ xb,
    const int* __restrict__ off, const int* __restrict__ cnt,
    const int* __restrict__ src, const float* __restrict__ wE, const float* __restrict__ dinv,
    const float* __restrict__ wgT, const float* __restrict__ bgp,
    const __bf16* __restrict__ wslh, const __bf16* __restrict__ wsll,
    const float* __restrict__ bsl, float* __restrict__ out) {
    __shared__ float axs[TT * 17];                   // aggregated x [t][c], pad 17
    __shared__ __align__(16) __bf16 xh[16 * 72];     // xlA^T hi [o][t]
    __shared__ __align__(16) __bf16 xl2[16 * 72];    // xlA^T lo
    int tid = threadIdx.x;
    int wave = tid >> 6, lane = tid & 63;
    int l15 = lane & 15, g = lane >> 4;
    int b = blockIdx.x & 7, n = blockIdx.x >> 3;     // XCD swizzle: batch = blk & 7
    size_t bn = (size_t)b * NN + n;

    // slin B-frags (wave-quadrant of wsl, L2-hot)
    int sglob = wave * 16 + l15;
    bf16x8 bh[2], bl[2];
#pragma unroll
    for (int k = 0; k < 2; k++) {
        bh[k] = __builtin_bit_cast(bf16x8, *(const float4*)(wslh + sglob * 64 + k * 32 + g * 8));
        bl[k] = __builtin_bit_cast(bf16x8, *(const float4*)(wsll + sglob * 64 + k * 32 + g * 8));
    }

    // ---- aggregate: self in f32 (exact), neighbors from bf16 xb (4 elems/thread) ----
    int o0 = off[n], cn = cnt[n];
    float d = dinv[n], d2 = d * d;
    float4 sf = ((const float4*)(x + bn * (TT * CC)))[tid];
    float a0 = d2 * sf.x, a1 = d2 * sf.y, a2 = d2 * sf.z, a3 = d2 * sf.w;
    const __bf16* xbb = xb + (size_t)b * NN * (TT * CC) + tid * 4;
    const int* srcp = src + o0;
    const float* wEp = wE + o0;
    int j = 0;
    for (; j + 4 <= cn; j += 4) {
        int s0 = srcp[j], s1 = srcp[j + 1], s2 = srcp[j + 2], s3 = srcp[j + 3];
        float w0 = wEp[j], w1 = wEp[j + 1], w2 = wEp[j + 2], w3 = wEp[j + 3];
        uint2 v0 = *(const uint2*)(xbb + (size_t)s0 * (TT * CC));
        uint2 v1 = *(const uint2*)(xbb + (size_t)s1 * (TT * CC));
        uint2 v2 = *(const uint2*)(xbb + (size_t)s2 * (TT * CC));
        uint2 v3 = *(const uint2*)(xbb + (size_t)s3 * (TT * CC));
        a0 = fmaf(w0, bflo(v0.x), fmaf(w1, bflo(v1.x), fmaf(w2, bflo(v2.x), fmaf(w3, bflo(v3.x), a0))));
        a1 = fmaf(w0, bfhi(v0.x), fmaf(w1, bfhi(v1.x), fmaf(w2, bfhi(v2.x), fmaf(w3, bfhi(v3.x), a1))));
        a2 = fmaf(w0, bflo(v0.y), fmaf(w1, bflo(v1.y), fmaf(w2, bflo(v2.y), fmaf(w3, bflo(v3.y), a2))));
        a3 = fmaf(w0, bfhi(v0.y), fmaf(w1, bfhi(v1.y), fmaf(w2, bfhi(v2.y), fmaf(w3, bfhi(v3.y), a3))));
    }
    for (; j < cn; j++) {
        int s = srcp[j];
        float w = wEp[j];
        uint2 v = *(const uint2*)(xbb + (size_t)s * (TT * CC));
        a0 = fmaf(w, bflo(v.x), a0); a1 = fmaf(w, bfhi(v.x), a1);
        a2 = fmaf(w, bflo(v.y), a2); a3 = fmaf(w, bfhi(v.y), a3);
    }
    {
        float* w = axs + (tid >> 2) * 17 + (tid & 3) * 4;
        w[0] = a0; w[1] = a1; w[2] = a2; w[3] = a3;
    }
    __syncthreads();

    // ---- transform (f32): lane = t, o = wave*4..+3; write xlA^T hi/lo bf16 ----
    {
        float p4[4];
#pragma unroll
        for (int q = 0; q < 4; q++) p4[q] = bgp[wave * 4 + q];
        const float* ar = axs + lane * 17;
#pragma unroll
        for (int c = 0; c < 16; c++) {
            float xv = ar[c];
#pragma unroll
            for (int q = 0; q < 4; q++)
                p4[q] = fmaf(wgT[c * 16 + wave * 4 + q], xv, p4[q]);
        }
#pragma unroll
        for (int q = 0; q < 4; q++) {
            int o = wave * 4 + q;
            __bf16 h = (__bf16)p4[q];
            xh[o * 72 + lane]  = h;
            xl2[o * 72 + lane] = (__bf16)(p4[q] - (float)h);
        }
    }
    __syncthreads();

    // ---- slin MFMA hi/lo: A lane l15 = o, k-chunk = kstep*32 + g*8 ----
    {
        float bv = bsl[sglob];
        f32x4 acc = (f32x4){bv, bv, bv, bv};
        bf16x8 ah[2], al[2];
#pragma unroll
        for (int k = 0; k < 2; k++) {
            ah[k] = __builtin_bit_cast(bf16x8, *(const float4*)(xh  + l15 * 72 + k * 32 + g * 8));
            al[k] = __builtin_bit_cast(bf16x8, *(const float4*)(xl2 + l15 * 72 + k * 32 + g * 8));
        }
#pragma unroll
        for (int k = 0; k < 2; k++) {
            acc = __builtin_amdgcn_mfma_f32_16x16x32_bf16(ah[k], bh[k], acc, 0, 0, 0);
            acc = __builtin_amdgcn_mfma_f32_16x16x32_bf16(al[k], bh[k], acc, 0, 0, 0);
            acc = __builtin_amdgcn_mfma_f32_16x16x32_bf16(ah[k], bl[k], acc, 0, 0, 0);
        }
        float4 o4;
        o4.x = tanh_fast(acc[0]); o4.y = tanh_fast(acc[1]);
        o4.z = tanh_fast(acc[2]); o4.w = tanh_fast(acc[3]);
        *(float4*)(out + (bn * TT + sglob) * CHO + 64 + g * 4) = o4;
    }
}

// ---------------- launch ----------------

extern "C" void kernel_launch(void* const* d_in, const int* in_sizes, int n_in,
                              void* d_out, int out_size, void* d_ws, size_t ws_size,
                              hipStream_t stream) {
    const float* x   = (const float*)d_in[0];
    const int*   ei  = (const int*)d_in[1];
    const float* w2  = (const float*)d_in[2];
    const float* b2  = (const float*)d_in[3];
    const float* w3  = (const float*)d_in[4];
    const float* b3  = (const float*)d_in[5];
    const float* w6  = (const float*)d_in[6];
    const float* b6  = (const float*)d_in[7];
    const float* w12 = (const float*)d_in[8];
    const float* b12 = (const float*)d_in[9];
    const float* wg  = (const float*)d_in[10];
    const float* bg  = (const float*)d_in[11];
    const float* wsl = (const float*)d_in[12];
    const float* bsl = (const float*)d_in[13];
    float* out = (float*)d_out;

    // ws layout (bytes): off|cnt|dinv|src|wE|wgT|bgp|bcat|wslh|wsll|wtg ... xb @4MB
    char*   ws   = (char*)d_ws;
    int*    off  = (int*)(ws);
    int*    cnt  = (int*)(ws + 4096);
    float*  dinv = (float*)(ws + 8192);
    int*    src  = (int*)(ws + 12288);
    float*  wE   = (float*)(ws + 77824);
    float*  wgT  = (float*)(ws + 143360);
    float*  bgp  = (float*)(ws + 144384);
    float*  bcat = (float*)(ws + 144448);
    __bf16* wslh = (__bf16*)(ws + 144704);
    __bf16* wsll = (__bf16*)(ws + 152896);
    __bf16* wtg  = (__bf16*)(ws + 161088);
    __bf16* xb   = (__bf16*)(ws + 4194304);

    k_prep<<<2062, 1024, 0, stream>>>(ei, x, w2, b2, w3, b3, w6, b6, w12, b12, wg, bg, wsl,
                                      off, cnt, dinv, src, wE, wgT, bgp, bcat,
                                      wslh, wsll, wtg, xb);
    k_tconv<<<BB * NN / 4, 256, 0, stream>>>(xb, wtg, bcat, out);
    k_gcn<<<BB * NN, 256, 0, stream>>>(x, xb, off, cnt, src, wE, dinv, wgT, bgp,
                                       wslh, wsll, bsl, out);
}